// Round 11
// baseline (90.153 us; speedup 1.0000x reference)
//
#include <hip/hip_runtime.h>
#include <hip/hip_bf16.h>
#include <hip/hip_fp16.h>
#include <math.h>

// NT-Xent: B=4096, D=128, N=8192, TEMP=0.5, label(i) = i ^ 4096
#define NB   4096
#define NTOT 8192
#define DD   128
#define ROWB 256          // bytes per zs row (128 f16)
#define NSLOT 64          // partial slots per row (64 col-chunks of 128)

typedef __attribute__((ext_vector_type(8))) _Float16 f16x8;
typedef __attribute__((ext_vector_type(4))) float    f32x4;

#if defined(__has_builtin)
#if __has_builtin(__builtin_amdgcn_exp2f)
#define EXP2F(x) __builtin_amdgcn_exp2f(x)
#else
#define EXP2F(x) exp2f(x)
#endif
#if __has_builtin(__builtin_amdgcn_logf)
#define LOG2F(x) __builtin_amdgcn_logf(x)
#else
#define LOG2F(x) log2f(x)
#endif
#else
#define EXP2F(x) exp2f(x)
#define LOG2F(x) log2f(x)
#endif

// Pre-scale normalized rows by sqrt(2*log2e) so MFMA emits acc = 2*log2e*dot.
// Then e = exp2(acc) directly, and loss_row = ln2*(log2(rowsum) - acc_label).
#define SQSCALE 1.69864394f   // sqrt(2.8853900817779268)
#define LN2     0.69314718056f

// zs rows are XOR-swizzled at 16-byte-block granularity:
//   physical_block = logical_block ^ (row & 15)
// keeps global_load_lds staging verbatim-contiguous while making the MFMA
// B-fragment ds_read_b128s 2-way-conflict (= free) instead of 16-way.

// ---------------- kernel 1: normalize+scale fp32 -> swizzled f16 -------------
__global__ void knorm(const float* __restrict__ zi, const float* __restrict__ zj,
                      _Float16* __restrict__ zs, float* __restrict__ out) {
  int wave = threadIdx.x >> 6, lane = threadIdx.x & 63;
  int j = lane & 31;                              // position within half-wave
  int row = (blockIdx.x << 3) + (wave << 1) + (lane >> 5);
  const float* src = (row < NB) ? (zi + (size_t)row * DD)
                                : (zj + (size_t)(row - NB) * DD);
  float4 v = ((const float4*)src)[j];             // 16 B per lane, 32 lanes/row
  float ss = v.x * v.x + v.y * v.y + v.z * v.z + v.w * v.w;
#pragma unroll
  for (int m = 1; m < 32; m <<= 1) ss += __shfl_xor(ss, m, 64);  // half-wave
  float inv = SQSCALE / fmaxf(sqrtf(ss), 1e-8f);
  struct H4 { _Float16 a, b, c, d; } hv;
  hv.a = (_Float16)(v.x * inv); hv.b = (_Float16)(v.y * inv);
  hv.c = (_Float16)(v.z * inv); hv.d = (_Float16)(v.w * inv);
  int phys = (j >> 1) ^ (row & 15);               // swizzle 16B block index
  char* dst = (char*)zs + (size_t)row * ROWB + phys * 16 + (j & 1) * 8;
  *(uint2*)dst = __builtin_bit_cast(uint2, hv);
  if (blockIdx.x == 0 && threadIdx.x == 0) out[0] = 0.f;
}

// async 16B/lane global->LDS copy (wave-uniform LDS base + lane*16)
__device__ __forceinline__ void gl_lds16(const char* g, char* l) {
  __builtin_amdgcn_global_load_lds(
      (const __attribute__((address_space(1))) void*)g,
      (__attribute__((address_space(3))) void*)l, 16, 0, 0);
}

// ------------- kernel 2: PERSISTENT symmetric sim GEMM + exp-sum -------------
// 2080 upper-tri 128x128 tiles, contiguous-assigned to 512 persistent blocks
// (~4 tiles each, 2 blocks/CU). R10 evidence: per-block fixed cost (~launch +
// A-load + cold stage + barrier drains) dominated at 1 tile/block (kmain ~30us
// both before & after halving work). Here: continuous double-buffered 32 KB
// B-panel pipeline, ONE barrier per tile, A-frags reused across same-rb tiles.
// Off-diag tiles emit row-side (slot cb) and col-side (slot rb) partials;
// col-side crosses waves via parity-buffered 2 KB LDS (race-free: one barrier
// serves staging-drain + transpose visibility).
__global__ __launch_bounds__(256) void kmain(const _Float16* __restrict__ zs,
                                             float* __restrict__ partial,
                                             float* __restrict__ slabel) {
  __shared__ f16x8 sB[2][2048];                  // 2 x 32 KB (128 cols x 256 B)
  __shared__ float cw[2][4][128];                // parity x wave x col (4 KB)
  int p  = blockIdx.x;
  int t0 = (p * 65) >> 4;                        // 2080/512 = 65/16 tiles/block
  int t1 = ((p + 1) * 65) >> 4;
  int n  = t1 - t0;
  int wave = threadIdx.x >> 6, lane = threadIdx.x & 63;
  int q = lane >> 4;        // 0..3
  int c = lane & 15;        // 0..15
  int d = c - (q << 2);     // reg r holds diag/label element when d == r

  // decode t0 -> (rb, cb):  S(rb) = 64*rb - rb*(rb-1)/2 tiles precede row rb
  int rb = (int)(64.5 - sqrt(64.5 * 64.5 - 2.0 * (double)t0));
  while (64 * (rb + 1) - ((rb + 1) * rb) / 2 <= t0) rb++;
  while (64 * rb - (rb * (rb - 1)) / 2 > t0) rb--;
  int cb = rb + (t0 - (64 * rb - (rb * (rb - 1)) / 2));

  f16x8 a[2][4];                                 // 2 strips x K=128
  auto loadA = [&](int r) {
#pragma unroll
    for (int st = 0; st < 2; st++) {
      const char* pp = (const char*)zs +
                       (size_t)(r * 128 + wave * 32 + st * 16 + c) * ROWB;
#pragma unroll
      for (int kk = 0; kk < 4; kk++)
        a[st][kk] = *(const f16x8*)(pp + (((kk << 2) + q) ^ c) * 16);
    }
  };
  auto stage = [&](int col_b, int par) {         // 32 KB B-panel for tile col
    const char* g = (const char*)zs + (size_t)col_b * 128 * ROWB + threadIdx.x * 16;
    char* l = (char*)&sB[par][0] + threadIdx.x * 16;
#pragma unroll
    for (int i = 0; i < 8; i++) gl_lds16(g + i * 4096, l + i * 4096);
  };

  loadA(rb);
  stage(cb, 0);
  __syncthreads();                               // drain first panel
  int par = 0;

  for (int i = 0; i < n; i++) {
    int nrb = rb, ncb = cb + 1;                  // next tile coords
    if (ncb == 64) { nrb = rb + 1; ncb = nrb; }
    if (i + 1 < n) stage(ncb, par ^ 1);          // prefetch next panel

    int rowbase = rb * 128 + wave * 32;
    int colchunk = cb * 128;
    bool diag = (rb == cb);
    float part[2][4] = {{0.f,0.f,0.f,0.f},{0.f,0.f,0.f,0.f}};
    float cpart[8] = {0,0,0,0,0,0,0,0};

#pragma unroll
    for (int tt = 0; tt < 8; tt++) {
      int colbase = colchunk + tt * 16;
      f16x8 b[4];
      const char* bp = (const char*)&sB[par][0] + (tt * 16 + c) * ROWB;
#pragma unroll
      for (int kk = 0; kk < 4; kk++)
        b[kk] = *(const f16x8*)(bp + (((kk << 2) + q) ^ c) * 16);
#pragma unroll
      for (int st = 0; st < 2; st++) {
        int sbase = rowbase + st * 16;
        f32x4 acc = {0.f, 0.f, 0.f, 0.f};
#pragma unroll
        for (int kk = 0; kk < 4; kk++)
          acc = __builtin_amdgcn_mfma_f32_16x16x32_f16(a[st][kk], b[kk], acc, 0, 0, 0);
        // C/D layout: col = lane&15, row = (lane>>4)*4 + reg
        if (colbase == (sbase ^ NB)) {           // label tile (wave-uniform)
#pragma unroll
          for (int r = 0; r < 4; r++)
            if (d == r) {
              slabel[sbase + c] = acc[r];
              slabel[(sbase + c) ^ NB] = acc[r]; // sim symmetric
            }
        }
        if (colbase == sbase) {                  // diag tile: mask self-sim
#pragma unroll
          for (int r = 0; r < 4; r++) {
            float e = (d == r) ? 0.f : EXP2F(acc[r]);
            part[st][r] += e; cpart[tt] += e;
          }
        } else {
#pragma unroll
          for (int r = 0; r < 4; r++) {
            float e = EXP2F(acc[r]);
            part[st][r] += e; cpart[tt] += e;
          }
        }
      }
    }

    // row-side: reduce across 16 lanes sharing a row; scatter-store (slot cb)
#pragma unroll
    for (int st = 0; st < 2; st++)
#pragma unroll
      for (int r = 0; r < 4; r++) {
        float v = part[st][r];
        v += __shfl_xor(v, 1, 64);
        v += __shfl_xor(v, 2, 64);
        v += __shfl_xor(v, 4, 64);
        v += __shfl_xor(v, 8, 64);
        if (c == 0)
          partial[(size_t)cb * NTOT + rowbase + st * 16 + (q << 2) + r] = v;
      }
    // col-side: reduce across the 4 quads (rows) of this wave into cw[par]
    if (!diag) {
#pragma unroll
      for (int tt = 0; tt < 8; tt++) {
        float v = cpart[tt];
        v += __shfl_xor(v, 16, 64);
        v += __shfl_xor(v, 32, 64);
        if (q == 0) cw[par][wave][tt * 16 + c] = v;
      }
    }
    __syncthreads();   // drains prefetch AND publishes cw[par]
    if (!diag && threadIdx.x < 128) {
      int col = threadIdx.x;
      float s = cw[par][0][col] + cw[par][1][col] +
                cw[par][2][col] + cw[par][3][col];
      partial[(size_t)rb * NTOT + colchunk + col] = s;   // slot rb
    }
    if (i + 1 < n && nrb != rb) loadA(nrb);      // new row-strip: reload A
    rb = nrb; cb = ncb; par ^= 1;
  }
}

// ---------------- kernel 3: finalize (sum 64 partials/row) -------------------
__global__ void kfinal(const float* __restrict__ partial,
                       const float* __restrict__ slabel,
                       float* __restrict__ out) {
  int i = blockIdx.x * 256 + threadIdx.x;        // 32 blocks * 256 = 8192 rows
  float s = 0.f;
#pragma unroll 8
  for (int k = 0; k < NSLOT; k++) s += partial[(size_t)k * NTOT + i];
  float acc = LN2 * (LOG2F(s) - slabel[i]);
#pragma unroll
  for (int m = 1; m < 64; m <<= 1) acc += __shfl_xor(acc, m, 64);
  __shared__ float wsum[4];
  int tid = threadIdx.x;
  if ((tid & 63) == 0) wsum[tid >> 6] = acc;
  __syncthreads();
  if (tid == 0)
    atomicAdd(out, (wsum[0] + wsum[1] + wsum[2] + wsum[3]) * (1.0f / (float)NTOT));
}

extern "C" void kernel_launch(void* const* d_in, const int* in_sizes, int n_in,
                              void* d_out, int out_size, void* d_ws, size_t ws_size,
                              hipStream_t stream) {
  const float* zi = (const float*)d_in[0];
  const float* zj = (const float*)d_in[1];
  float* out = (float*)d_out;

  char* ws = (char*)d_ws;
  const size_t ZS_BYTES = (size_t)NTOT * DD * sizeof(_Float16);      // 2 MiB
  _Float16* zs   = (_Float16*)ws;
  float* partial = (float*)(ws + ZS_BYTES);                          // 2 MiB
  float* slabel  = (float*)(ws + ZS_BYTES + (size_t)NSLOT * NTOT * 4);

  knorm<<<NTOT / 8, 256, 0, stream>>>(zi, zj, zs, out);
  kmain<<<512, 256, 0, stream>>>(zs, partial, slabel);
  kfinal<<<NTOT / 256, 256, 0, stream>>>(partial, slabel, out);
}

// Round 12
// 90.134 us; speedup vs baseline: 1.0002x; 1.0002x over previous
//
#include <hip/hip_runtime.h>
#include <hip/hip_bf16.h>
#include <hip/hip_fp16.h>

// NT-Xent: B=4096, D=128, N=8192, TEMP=0.5, label(i) = i ^ 4096
#define NB   4096
#define NTOT 8192
#define DD   128
#define ROWB 256          // bytes per zs row (128 f16)
#define NSLOT 64          // partial slots per row (64 col-chunks of 128)

typedef __attribute__((ext_vector_type(8))) _Float16 f16x8;
typedef __attribute__((ext_vector_type(4))) float    f32x4;

#if defined(__has_builtin)
#if __has_builtin(__builtin_amdgcn_exp2f)
#define EXP2F(x) __builtin_amdgcn_exp2f(x)
#else
#define EXP2F(x) exp2f(x)
#endif
#if __has_builtin(__builtin_amdgcn_logf)
#define LOG2F(x) __builtin_amdgcn_logf(x)
#else
#define LOG2F(x) log2f(x)
#endif
#else
#define EXP2F(x) exp2f(x)
#define LOG2F(x) log2f(x)
#endif

// Pre-scale normalized rows by sqrt(2*log2e) so MFMA emits acc = 2*log2e*dot.
// Then e = exp2(acc) directly, and loss_row = ln2*(log2(rowsum) - acc_label).
#define SQSCALE 1.69864394f   // sqrt(2.8853900817779268)
#define LN2     0.69314718056f

// zs rows are XOR-swizzled at 16-byte-block granularity:
//   physical_block = logical_block ^ (row & 15)
// keeps global_load_lds staging verbatim-contiguous while making the MFMA
// B-fragment ds_read_b128s 2-way-conflict (= free) instead of 16-way.

// ---------------- kernel 1: normalize+scale fp32 -> swizzled f16 -------------
__global__ void knorm(const float* __restrict__ zi, const float* __restrict__ zj,
                      _Float16* __restrict__ zs, float* __restrict__ out) {
  int wave = threadIdx.x >> 6, lane = threadIdx.x & 63;
  int j = lane & 31;                              // position within half-wave
  int row = (blockIdx.x << 3) + (wave << 1) + (lane >> 5);
  const float* src = (row < NB) ? (zi + (size_t)row * DD)
                                : (zj + (size_t)(row - NB) * DD);
  float4 v = ((const float4*)src)[j];             // 16 B per lane, 32 lanes/row
  float ss = v.x * v.x + v.y * v.y + v.z * v.z + v.w * v.w;
#pragma unroll
  for (int m = 1; m < 32; m <<= 1) ss += __shfl_xor(ss, m, 64);  // half-wave
  float inv = SQSCALE / fmaxf(sqrtf(ss), 1e-8f);
  struct H4 { _Float16 a, b, c, d; } hv;
  hv.a = (_Float16)(v.x * inv); hv.b = (_Float16)(v.y * inv);
  hv.c = (_Float16)(v.z * inv); hv.d = (_Float16)(v.w * inv);
  int phys = (j >> 1) ^ (row & 15);               // swizzle 16B block index
  char* dst = (char*)zs + (size_t)row * ROWB + phys * 16 + (j & 1) * 8;
  *(uint2*)dst = __builtin_bit_cast(uint2, hv);
  if (blockIdx.x == 0 && threadIdx.x == 0) out[0] = 0.f;
}

// async 16B/lane global->LDS copy (wave-uniform LDS base + lane*16)
__device__ __forceinline__ void gl_lds16(const char* g, char* l) {
  __builtin_amdgcn_global_load_lds(
      (const __attribute__((address_space(1))) void*)g,
      (__attribute__((address_space(3))) void*)l, 16, 0, 0);
}

// ---------------- kernel 2: SYMMETRIC sim GEMM + streaming exp-sum -----------
// R10 base (best: 89.1us). ONE change: split each K=128 MFMA chain into TWO
// independent accumulators (kk 0,2 / kk 1,3), summed at the end. Theory: the
// work-normalized ~1M elem/us invariance across R1/R5-R11 (work halving,
// occupancy 9->47%, staging, persistence all neutral) points at dependent-MFMA
// latency chains (4-deep per tile) as the serialized resource; this halves
// chain depth -> 4 independent 2-chains per col-tile (with the 2 row strips).
__global__ __launch_bounds__(256) void kmain(const _Float16* __restrict__ zs,
                                             float* __restrict__ partial,
                                             float* __restrict__ slabel) {
  int rb = blockIdx.x >> 6;
  int cb = blockIdx.x & 63;
  if (cb < rb) return;                           // lower triangle: dead block
  __shared__ f16x8 sB[2][1024];                  // 2 x 16 KB (64 cols x 256 B)
  int wave  = threadIdx.x >> 6;
  int lane  = threadIdx.x & 63;
  int q = lane >> 4;        // 0..3
  int c = lane & 15;        // 0..15
  int d = c - (q << 2);     // reg r holds diag/label element when d == r
  int rowbase = rb * 128 + wave * 32;
  int colchunk = cb * 128;
  bool diagblk = (rb == cb);

  // A fragments: 2 strips of 16 rows, K=128 (4 k-frags of 32) = 32 VGPRs
  f16x8 a[2][4];
#pragma unroll
  for (int st = 0; st < 2; st++) {
    const char* p = (const char*)zs + (size_t)(rowbase + st * 16 + c) * ROWB;
#pragma unroll
    for (int kk = 0; kk < 4; kk++)
      a[st][kk] = *(const f16x8*)(p + (((kk << 2) + q) ^ c) * 16);
  }

  float part[2][4] = {{0.f,0.f,0.f,0.f},{0.f,0.f,0.f,0.f}};  // row-side
  float cpart[8] = {0,0,0,0,0,0,0,0};            // col-side: col = tt*16 + c

  const char* gB = (const char*)zs + (size_t)colchunk * ROWB;
  int soff = wave * 4096 + lane * 16;            // this wave's 4 KB slice

  auto stage = [&](int s) {                      // 16 KB: cols colchunk+s*64..
    const char* g = gB + (size_t)s * (64 * ROWB) + soff;
    char* l = (char*)&sB[s & 1][0] + soff;
    gl_lds16(g, l);
    gl_lds16(g + 1024, l + 1024);
    gl_lds16(g + 2048, l + 2048);
    gl_lds16(g + 3072, l + 3072);
  };

  auto compute = [&](int s) {
    const char* base = (const char*)&sB[s & 1][0];
#pragma unroll
    for (int t = 0; t < 4; t++) {
      int tt = s * 4 + t;                        // col tile idx within block
      int colbase = colchunk + tt * 16;
      f16x8 b[4];
      const char* bp = base + (t * 16 + c) * ROWB;
#pragma unroll
      for (int kk = 0; kk < 4; kk++)
        b[kk] = *(const f16x8*)(bp + (((kk << 2) + q) ^ c) * 16);

      // 4 independent 2-deep MFMA chains (2 strips x 2 split-K accumulators)
      f32x4 e0[2], e1[2];
#pragma unroll
      for (int st = 0; st < 2; st++) {
        e0[st] = (f32x4){0.f, 0.f, 0.f, 0.f};
        e1[st] = (f32x4){0.f, 0.f, 0.f, 0.f};
      }
#pragma unroll
      for (int st = 0; st < 2; st++) {
        e0[st] = __builtin_amdgcn_mfma_f32_16x16x32_f16(a[st][0], b[0], e0[st], 0, 0, 0);
        e1[st] = __builtin_amdgcn_mfma_f32_16x16x32_f16(a[st][1], b[1], e1[st], 0, 0, 0);
      }
#pragma unroll
      for (int st = 0; st < 2; st++) {
        e0[st] = __builtin_amdgcn_mfma_f32_16x16x32_f16(a[st][2], b[2], e0[st], 0, 0, 0);
        e1[st] = __builtin_amdgcn_mfma_f32_16x16x32_f16(a[st][3], b[3], e1[st], 0, 0, 0);
      }

#pragma unroll
      for (int st = 0; st < 2; st++) {
        int sbase = rowbase + st * 16;
        f32x4 acc = e0[st] + e1[st];
        // C/D layout: col = lane&15, row = (lane>>4)*4 + reg
        if (colbase == (sbase ^ NB)) {           // label tile (wave-uniform)
#pragma unroll
          for (int r = 0; r < 4; r++)
            if (d == r) {
              slabel[sbase + c] = acc[r];        // row i
              slabel[(sbase + c) ^ NB] = acc[r]; // partner row (sim symmetric)
            }
        }
        if (colbase == sbase) {                  // diag tile: mask self-sim
#pragma unroll
          for (int r = 0; r < 4; r++) {
            float e = (d == r) ? 0.f : EXP2F(acc[r]);
            part[st][r] += e;
            cpart[tt]   += e;                    // unused in diag blocks
          }
        } else {
#pragma unroll
          for (int r = 0; r < 4; r++) {
            float e = EXP2F(acc[r]);
            part[st][r] += e;
            cpart[tt]   += e;
          }
        }
      }
    }
  };

  stage(0);
  __syncthreads();                               // drain stage 0
  for (int s = 0; s < 2; s++) {
    if (s + 1 < 2) stage(s + 1);                 // prefetch (overlaps compute)
    compute(s);
    __syncthreads();                             // drain prefetch; protect buf
  }

  // epilogue: sB is dead; alias it for both transposes
  float* ebuf  = (float*)&sB[0][0];              // 128 floats: row sums
  float* cwave = ebuf + 128;                     // 4 x 128: per-wave col sums

  // row side: reduce across the 16 lanes sharing a row
#pragma unroll
  for (int st = 0; st < 2; st++)
#pragma unroll
    for (int r = 0; r < 4; r++) {
      float v = part[st][r];
      v += __shfl_xor(v, 1, 64);
      v += __shfl_xor(v, 2, 64);
      v += __shfl_xor(v, 4, 64);
      v += __shfl_xor(v, 8, 64);
      if (c == 0) ebuf[wave * 32 + st * 16 + (q << 2) + r] = v;
    }
  // col side: reduce across the 4 quads (rows) sharing a col
  if (!diagblk) {
#pragma unroll
    for (int tt = 0; tt < 8; tt++) {
      float v = cpart[tt];
      v += __shfl_xor(v, 16, 64);
      v += __shfl_xor(v, 32, 64);
      if (q == 0) cwave[wave * 128 + tt * 16 + c] = v;
    }
  }
  __syncthreads();
  if (threadIdx.x < 128) {
    // row-side partial: slot cb, rows rb*128..+127
    partial[(size_t)cb * NTOT + rb * 128 + threadIdx.x] = ebuf[threadIdx.x];
  } else if (!diagblk) {
    // col-side partial: slot rb, rows cb*128..+127 (cols of this block)
    int col = threadIdx.x - 128;
    float s = cwave[col] + cwave[128 + col] + cwave[256 + col] + cwave[384 + col];
    partial[(size_t)rb * NTOT + cb * 128 + col] = s;
  }
}

// ---------------- kernel 3: finalize (sum 64 partials/row) -------------------
__global__ void kfinal(const float* __restrict__ partial,
                       const float* __restrict__ slabel,
                       float* __restrict__ out) {
  int i = blockIdx.x * 256 + threadIdx.x;        // 32 blocks * 256 = 8192 rows
  float s = 0.f;
#pragma unroll 8
  for (int k = 0; k < NSLOT; k++) s += partial[(size_t)k * NTOT + i];
  float acc = LN2 * (LOG2F(s) - slabel[i]);
#pragma unroll
  for (int m = 1; m < 64; m <<= 1) acc += __shfl_xor(acc, m, 64);
  __shared__ float wsum[4];
  int tid = threadIdx.x;
  if ((tid & 63) == 0) wsum[tid >> 6] = acc;
  __syncthreads();
  if (tid == 0)
    atomicAdd(out, (wsum[0] + wsum[1] + wsum[2] + wsum[3]) * (1.0f / (float)NTOT));
}

extern "C" void kernel_launch(void* const* d_in, const int* in_sizes, int n_in,
                              void* d_out, int out_size, void* d_ws, size_t ws_size,
                              hipStream_t stream) {
  const float* zi = (const float*)d_in[0];
  const float* zj = (const float*)d_in[1];
  float* out = (float*)d_out;

  char* ws = (char*)d_ws;
  const size_t ZS_BYTES = (size_t)NTOT * DD * sizeof(_Float16);      // 2 MiB
  _Float16* zs   = (_Float16*)ws;
  float* partial = (float*)(ws + ZS_BYTES);                          // 2 MiB
  float* slabel  = (float*)(ws + ZS_BYTES + (size_t)NSLOT * NTOT * 4);

  knorm<<<NTOT / 8, 256, 0, stream>>>(zi, zj, zs, out);
  kmain<<<64 * 64, 256, 0, stream>>>(zs, partial, slabel);   // upper-tri live
  kfinal<<<NTOT / 256, 256, 0, stream>>>(partial, slabel, out);
}

// Round 13
// 84.651 us; speedup vs baseline: 1.0650x; 1.0648x over previous
//
#include <hip/hip_runtime.h>
#include <hip/hip_bf16.h>
#include <hip/hip_fp16.h>
#include <math.h>

// NT-Xent: B=4096, D=128, N=8192, TEMP=0.5, label(i) = i ^ 4096
#define NB   4096
#define NTOT 8192
#define DD   128
#define ROWB 256          // bytes per zs row (128 f16)
#define NSLOT 64          // partial slots per row (64 col-chunks of 128)

typedef __attribute__((ext_vector_type(8))) _Float16 f16x8;
typedef __attribute__((ext_vector_type(4))) float    f32x4;

#if defined(__has_builtin)
#if __has_builtin(__builtin_amdgcn_exp2f)
#define EXP2F(x) __builtin_amdgcn_exp2f(x)
#else
#define EXP2F(x) exp2f(x)
#endif
#if __has_builtin(__builtin_amdgcn_logf)
#define LOG2F(x) __builtin_amdgcn_logf(x)
#else
#define LOG2F(x) log2f(x)
#endif
#else
#define EXP2F(x) exp2f(x)
#define LOG2F(x) log2f(x)
#endif

// Pre-scale normalized rows by sqrt(2*log2e) so MFMA emits acc = 2*log2e*dot.
// Then e = exp2(acc) directly, and loss_row = ln2*(log2(rowsum) - acc_label).
#define SQSCALE 1.69864394f   // sqrt(2.8853900817779268)
#define LN2     0.69314718056f

// zs rows are XOR-swizzled at 16-byte-block granularity:
//   physical_block = logical_block ^ (row & 15)
// keeps global_load_lds staging verbatim-contiguous while making the MFMA
// B-fragment ds_read_b128s 2-way-conflict (= free) instead of 16-way.

// ---------------- kernel 1: normalize+scale fp32 -> swizzled f16 -------------
__global__ void knorm(const float* __restrict__ zi, const float* __restrict__ zj,
                      _Float16* __restrict__ zs, float* __restrict__ out) {
  int wave = threadIdx.x >> 6, lane = threadIdx.x & 63;
  int j = lane & 31;                              // position within half-wave
  int row = (blockIdx.x << 3) + (wave << 1) + (lane >> 5);
  const float* src = (row < NB) ? (zi + (size_t)row * DD)
                                : (zj + (size_t)(row - NB) * DD);
  float4 v = ((const float4*)src)[j];             // 16 B per lane, 32 lanes/row
  float ss = v.x * v.x + v.y * v.y + v.z * v.z + v.w * v.w;
#pragma unroll
  for (int m = 1; m < 32; m <<= 1) ss += __shfl_xor(ss, m, 64);  // half-wave
  float inv = SQSCALE / fmaxf(sqrtf(ss), 1e-8f);
  struct H4 { _Float16 a, b, c, d; } hv;
  hv.a = (_Float16)(v.x * inv); hv.b = (_Float16)(v.y * inv);
  hv.c = (_Float16)(v.z * inv); hv.d = (_Float16)(v.w * inv);
  int phys = (j >> 1) ^ (row & 15);               // swizzle 16B block index
  char* dst = (char*)zs + (size_t)row * ROWB + phys * 16 + (j & 1) * 8;
  *(uint2*)dst = __builtin_bit_cast(uint2, hv);
  if (blockIdx.x == 0 && threadIdx.x == 0) out[0] = 0.f;
}

// async 16B/lane global->LDS copy (wave-uniform LDS base + lane*16)
__device__ __forceinline__ void gl_lds16(const char* g, char* l) {
  __builtin_amdgcn_global_load_lds(
      (const __attribute__((address_space(1))) void*)g,
      (__attribute__((address_space(3))) void*)l, 16, 0, 0);
}

// ---------------- kernel 2: SYMMETRIC sim GEMM + streaming exp-sum -----------
// R10 base (best: 89.1us). R13 trims: exact 2080-block grid (no dead blocks),
// 8 KB double-buffered stages (LDS 16 KB -> occupancy VGPR-capped ~62% not
// LDS-capped 50%; half the bytes per barrier drain), vectorized f32x4 row
// accumulators + pairwise col sums (fewer VALU adds).
__global__ __launch_bounds__(256) void kmain(const _Float16* __restrict__ zs,
                                             float* __restrict__ partial,
                                             float* __restrict__ slabel) {
  // decode linear upper-tri tile id -> (rb, cb), rb <= cb (R11-verified)
  int t0 = blockIdx.x;
  int rb = (int)(64.5 - sqrt(64.5 * 64.5 - 2.0 * (double)t0));
  while (64 * (rb + 1) - ((rb + 1) * rb) / 2 <= t0) rb++;
  while (64 * rb - (rb * (rb - 1)) / 2 > t0) rb--;
  int cb = rb + (t0 - (64 * rb - (rb * (rb - 1)) / 2));

  __shared__ f16x8 sB[2][512];                   // 2 x 8 KB (32 cols x 256 B)
  int wave  = threadIdx.x >> 6;
  int lane  = threadIdx.x & 63;
  int q = lane >> 4;        // 0..3
  int c = lane & 15;        // 0..15
  int d = c - (q << 2);     // reg r holds diag/label element when d == r
  int rowbase = rb * 128 + wave * 32;
  int colchunk = cb * 128;
  bool diagblk = (rb == cb);

  // A fragments: 2 strips of 16 rows, K=128 (4 k-frags of 32) = 32 VGPRs
  f16x8 a[2][4];
#pragma unroll
  for (int st = 0; st < 2; st++) {
    const char* p = (const char*)zs + (size_t)(rowbase + st * 16 + c) * ROWB;
#pragma unroll
    for (int kk = 0; kk < 4; kk++)
      a[st][kk] = *(const f16x8*)(p + (((kk << 2) + q) ^ c) * 16);
  }

  f32x4 part[2] = {{0.f,0.f,0.f,0.f},{0.f,0.f,0.f,0.f}};     // row-side
  float cpart[8] = {0,0,0,0,0,0,0,0};            // col-side: col = tt*16 + c

  const char* gB = (const char*)zs + (size_t)colchunk * ROWB;
  int soff = wave * 2048 + lane * 16;            // this wave's 2 KB slice

  auto stage = [&](int s) {                      // 8 KB: cols colchunk+s*32..
    const char* g = gB + (size_t)s * (32 * ROWB) + soff;
    char* l = (char*)&sB[s & 1][0] + soff;
    gl_lds16(g, l);
    gl_lds16(g + 1024, l + 1024);
  };

  auto compute = [&](int s) {
    const char* base = (const char*)&sB[s & 1][0];
#pragma unroll
    for (int t = 0; t < 2; t++) {
      int tt = s * 2 + t;                        // col tile idx within block
      int colbase = colchunk + tt * 16;
      f16x8 b[4];
      const char* bp = base + (t * 16 + c) * ROWB;
#pragma unroll
      for (int kk = 0; kk < 4; kk++)
        b[kk] = *(const f16x8*)(bp + (((kk << 2) + q) ^ c) * 16);
#pragma unroll
      for (int st = 0; st < 2; st++) {
        int sbase = rowbase + st * 16;
        f32x4 acc = {0.f, 0.f, 0.f, 0.f};
#pragma unroll
        for (int kk = 0; kk < 4; kk++)
          acc = __builtin_amdgcn_mfma_f32_16x16x32_f16(a[st][kk], b[kk], acc, 0, 0, 0);
        // C/D layout: col = lane&15, row = (lane>>4)*4 + reg
        if (colbase == (sbase ^ NB)) {           // label tile (wave-uniform)
#pragma unroll
          for (int r = 0; r < 4; r++)
            if (d == r) {
              slabel[sbase + c] = acc[r];        // row i
              slabel[(sbase + c) ^ NB] = acc[r]; // partner row (sim symmetric)
            }
        }
        f32x4 e;
        if (colbase == sbase) {                  // diag tile: mask self-sim
#pragma unroll
          for (int r = 0; r < 4; r++)
            e[r] = (d == r) ? 0.f : EXP2F(acc[r]);
        } else {
#pragma unroll
          for (int r = 0; r < 4; r++)
            e[r] = EXP2F(acc[r]);
        }
        part[st] += e;                           // vector add (pk-able)
        cpart[tt] += (e[0] + e[1]) + (e[2] + e[3]);  // pairwise
      }
    }
  };

  stage(0);
  __syncthreads();                               // drain stage 0
  for (int s = 0; s < 4; s++) {
    if (s + 1 < 4) stage(s + 1);                 // prefetch (overlaps compute)
    compute(s);
    __syncthreads();                             // drain prefetch; protect buf
  }

  // epilogue: sB is dead; alias it for both transposes
  float* ebuf  = (float*)&sB[0][0];              // 128 floats: row sums
  float* cwave = ebuf + 128;                     // 4 x 128: per-wave col sums

  // row side: reduce across the 16 lanes sharing a row
#pragma unroll
  for (int st = 0; st < 2; st++)
#pragma unroll
    for (int r = 0; r < 4; r++) {
      float v = part[st][r];
      v += __shfl_xor(v, 1, 64);
      v += __shfl_xor(v, 2, 64);
      v += __shfl_xor(v, 4, 64);
      v += __shfl_xor(v, 8, 64);
      if (c == 0) ebuf[wave * 32 + st * 16 + (q << 2) + r] = v;
    }
  // col side: reduce across the 4 quads (rows) sharing a col
  if (!diagblk) {
#pragma unroll
    for (int tt = 0; tt < 8; tt++) {
      float v = cpart[tt];
      v += __shfl_xor(v, 16, 64);
      v += __shfl_xor(v, 32, 64);
      if (q == 0) cwave[wave * 128 + tt * 16 + c] = v;
    }
  }
  __syncthreads();
  if (threadIdx.x < 128) {
    // row-side partial: slot cb, rows rb*128..+127
    partial[(size_t)cb * NTOT + rb * 128 + threadIdx.x] = ebuf[threadIdx.x];
  } else if (!diagblk) {
    // col-side partial: slot rb, rows cb*128..+127 (cols of this block)
    int col = threadIdx.x - 128;
    float s = (cwave[col] + cwave[128 + col]) + (cwave[256 + col] + cwave[384 + col]);
    partial[(size_t)rb * NTOT + cb * 128 + col] = s;
  }
}

// ---------------- kernel 3: finalize (sum 64 partials/row) -------------------
__global__ void kfinal(const float* __restrict__ partial,
                       const float* __restrict__ slabel,
                       float* __restrict__ out) {
  int i = blockIdx.x * 256 + threadIdx.x;        // 32 blocks * 256 = 8192 rows
  float s = 0.f;
#pragma unroll 8
  for (int k = 0; k < NSLOT; k++) s += partial[(size_t)k * NTOT + i];
  float acc = LN2 * (LOG2F(s) - slabel[i]);
#pragma unroll
  for (int m = 1; m < 64; m <<= 1) acc += __shfl_xor(acc, m, 64);
  __shared__ float wsum[4];
  int tid = threadIdx.x;
  if ((tid & 63) == 0) wsum[tid >> 6] = acc;
  __syncthreads();
  if (tid == 0)
    atomicAdd(out, (wsum[0] + wsum[1] + wsum[2] + wsum[3]) * (1.0f / (float)NTOT));
}

extern "C" void kernel_launch(void* const* d_in, const int* in_sizes, int n_in,
                              void* d_out, int out_size, void* d_ws, size_t ws_size,
                              hipStream_t stream) {
  const float* zi = (const float*)d_in[0];
  const float* zj = (const float*)d_in[1];
  float* out = (float*)d_out;

  char* ws = (char*)d_ws;
  const size_t ZS_BYTES = (size_t)NTOT * DD * sizeof(_Float16);      // 2 MiB
  _Float16* zs   = (_Float16*)ws;
  float* partial = (float*)(ws + ZS_BYTES);                          // 2 MiB
  float* slabel  = (float*)(ws + ZS_BYTES + (size_t)NSLOT * NTOT * 4);

  knorm<<<NTOT / 8, 256, 0, stream>>>(zi, zj, zs, out);
  kmain<<<2080, 256, 0, stream>>>(zs, partial, slabel);      // exact upper-tri
  kfinal<<<NTOT / 256, 256, 0, stream>>>(partial, slabel, out);
}